// Round 1
// baseline (2325.552 us; speedup 1.0000x reference)
//
#include <hip/hip_runtime.h>
#include <hip/hip_fp16.h>

#define EPSF 1e-12f

constexpr int NB = 16;          // batches
constexpr int N  = 2048;        // matrix dim
constexpr int NR = NB * N;      // 32768 rows; also length of r/c/t
constexpr long long NELEM = (long long)NB * N * N;  // 67108864
constexpr int CHUNK = 32;       // rows per col-pass block

// ---------------- init r=c=1, t=0 (ws is poisoned 0xAA every call) ----------
__global__ void init_vecs(float* __restrict__ r, float* __restrict__ c,
                          float* __restrict__ t) {
    int i = blockIdx.x * blockDim.x + threadIdx.x;
    if (i < NR) { r[i] = 1.f; c[i] = 1.f; t[i] = 0.f; }
}

// ---------------- c update + zero t for next iteration ----------------------
__global__ void c_update(float* __restrict__ c, float* __restrict__ t) {
    int i = blockIdx.x * blockDim.x + threadIdx.x;
    if (i < NR) {
        float cv = c[i], tv = t[i];
        c[i] = cv / (cv * tv + EPSF);
        t[i] = 0.f;
    }
}

// ======================= fp16-E path (E cached in ws) =======================

__global__ void exp_cast(const float* __restrict__ A, __half* __restrict__ E) {
    long long g = ((long long)blockIdx.x * blockDim.x + threadIdx.x) * 8;
    float4 a0 = *reinterpret_cast<const float4*>(A + g);
    float4 a1 = *reinterpret_cast<const float4*>(A + g + 4);
    union { __half2 h2[4]; uint4 u; } cvt;
    cvt.h2[0] = __floats2half2_rn(expf(a0.x), expf(a0.y));
    cvt.h2[1] = __floats2half2_rn(expf(a0.z), expf(a0.w));
    cvt.h2[2] = __floats2half2_rn(expf(a1.x), expf(a1.y));
    cvt.h2[3] = __floats2half2_rn(expf(a1.z), expf(a1.w));
    *reinterpret_cast<uint4*>(E + g) = cvt.u;
}

// one wave (64 lanes) per row; 4 rows per 256-thread block
__global__ __launch_bounds__(256) void row_pass_h(const __half* __restrict__ E,
                                                  const float* __restrict__ c,
                                                  float* __restrict__ r) {
    int lane = threadIdx.x & 63;
    int R = blockIdx.x * 4 + (threadIdx.x >> 6);
    int b = R >> 11;
    const __half* row = E + (long long)R * N;
    const float*  cb  = c + b * N;
    float acc = 0.f;
#pragma unroll
    for (int k = 0; k < 4; ++k) {
        int j = k * 512 + lane * 8;
        uint4 hv = *reinterpret_cast<const uint4*>(row + j);
        const __half2* h2 = reinterpret_cast<const __half2*>(&hv);
        float4 c0 = *reinterpret_cast<const float4*>(cb + j);
        float4 c1 = *reinterpret_cast<const float4*>(cb + j + 4);
        float2 f0 = __half22float2(h2[0]);
        float2 f1 = __half22float2(h2[1]);
        float2 f2 = __half22float2(h2[2]);
        float2 f3 = __half22float2(h2[3]);
        acc += f0.x * c0.x + f0.y * c0.y + f1.x * c0.z + f1.y * c0.w
             + f2.x * c1.x + f2.y * c1.y + f3.x * c1.z + f3.y * c1.w;
    }
#pragma unroll
    for (int off = 32; off > 0; off >>= 1) acc += __shfl_xor(acc, off, 64);
    if (lane == 0) {
        float rv = r[R];
        r[R] = rv / (rv * acc + EPSF);
    }
}

// each 256-thread block covers all 2048 columns of one batch (8 cols/thread),
// over a CHUNK-row slice; partial sums accumulated into t via atomics
__global__ __launch_bounds__(256) void col_pass_h(const __half* __restrict__ E,
                                                  const float* __restrict__ r,
                                                  float* __restrict__ t) {
    int b     = blockIdx.x >> 6;   // 64 chunks per batch (2048/32)
    int chunk = blockIdx.x & 63;
    int j0 = threadIdx.x * 8;
    const __half* base = E + (long long)b * N * N + (long long)(chunk * CHUNK) * N + j0;
    const float* rb = r + b * N + chunk * CHUNK;
    float acc[8] = {0.f, 0.f, 0.f, 0.f, 0.f, 0.f, 0.f, 0.f};
#pragma unroll 4
    for (int i = 0; i < CHUNK; ++i) {
        float rv = rb[i];
        uint4 hv = *reinterpret_cast<const uint4*>(base + (long long)i * N);
        const __half2* h2 = reinterpret_cast<const __half2*>(&hv);
        float2 f0 = __half22float2(h2[0]);
        float2 f1 = __half22float2(h2[1]);
        float2 f2 = __half22float2(h2[2]);
        float2 f3 = __half22float2(h2[3]);
        acc[0] += rv * f0.x; acc[1] += rv * f0.y;
        acc[2] += rv * f1.x; acc[3] += rv * f1.y;
        acc[4] += rv * f2.x; acc[5] += rv * f2.y;
        acc[6] += rv * f3.x; acc[7] += rv * f3.y;
    }
    float* tb = t + b * N + j0;
#pragma unroll
    for (int k = 0; k < 8; ++k) atomicAdd(tb + k, acc[k]);
}

__global__ void out_h(const __half* __restrict__ E, const float* __restrict__ r,
                      const float* __restrict__ c, float* __restrict__ out) {
    long long g = ((long long)blockIdx.x * blockDim.x + threadIdx.x) * 8;
    int R = (int)(g >> 11);
    int b = R >> 11;
    int j = (int)(g & 2047);
    float rv = r[R];
    const float* cb = c + b * N + j;
    float4 c0 = *reinterpret_cast<const float4*>(cb);
    float4 c1 = *reinterpret_cast<const float4*>(cb + 4);
    uint4 hv = *reinterpret_cast<const uint4*>(E + g);
    const __half2* h2 = reinterpret_cast<const __half2*>(&hv);
    float2 f0 = __half22float2(h2[0]);
    float2 f1 = __half22float2(h2[1]);
    float2 f2 = __half22float2(h2[2]);
    float2 f3 = __half22float2(h2[3]);
    float4 o0, o1;
    o0.x = rv * f0.x * c0.x; o0.y = rv * f0.y * c0.y;
    o0.z = rv * f1.x * c0.z; o0.w = rv * f1.y * c0.w;
    o1.x = rv * f2.x * c1.x; o1.y = rv * f2.y * c1.y;
    o1.z = rv * f3.x * c1.z; o1.w = rv * f3.y * c1.w;
    *reinterpret_cast<float4*>(out + g)     = o0;
    *reinterpret_cast<float4*>(out + g + 4) = o1;
}

// ================= fallback path: recompute exp(A) every pass ===============

__global__ __launch_bounds__(256) void row_pass_f(const float* __restrict__ A,
                                                  const float* __restrict__ c,
                                                  float* __restrict__ r) {
    int lane = threadIdx.x & 63;
    int R = blockIdx.x * 4 + (threadIdx.x >> 6);
    int b = R >> 11;
    const float* row = A + (long long)R * N;
    const float* cb  = c + b * N;
    float acc = 0.f;
#pragma unroll
    for (int k = 0; k < 8; ++k) {
        int j = k * 256 + lane * 4;
        float4 a  = *reinterpret_cast<const float4*>(row + j);
        float4 cv = *reinterpret_cast<const float4*>(cb + j);
        acc += __expf(a.x) * cv.x + __expf(a.y) * cv.y
             + __expf(a.z) * cv.z + __expf(a.w) * cv.w;
    }
#pragma unroll
    for (int off = 32; off > 0; off >>= 1) acc += __shfl_xor(acc, off, 64);
    if (lane == 0) {
        float rv = r[R];
        r[R] = rv / (rv * acc + EPSF);
    }
}

__global__ __launch_bounds__(256) void col_pass_f(const float* __restrict__ A,
                                                  const float* __restrict__ r,
                                                  float* __restrict__ t) {
    int b     = blockIdx.x >> 7;       // 128 blocks per batch
    int rem   = blockIdx.x & 127;
    int cblk  = rem >> 6;              // 0..1 (1024 cols each)
    int chunk = rem & 63;              // 0..63
    int j0 = cblk * 1024 + threadIdx.x * 4;
    const float* base = A + (long long)b * N * N + (long long)(chunk * CHUNK) * N + j0;
    const float* rb = r + b * N + chunk * CHUNK;
    float acc[4] = {0.f, 0.f, 0.f, 0.f};
#pragma unroll 4
    for (int i = 0; i < CHUNK; ++i) {
        float rv = rb[i];
        float4 a = *reinterpret_cast<const float4*>(base + (long long)i * N);
        acc[0] += rv * __expf(a.x); acc[1] += rv * __expf(a.y);
        acc[2] += rv * __expf(a.z); acc[3] += rv * __expf(a.w);
    }
    float* tb = t + b * N + j0;
#pragma unroll
    for (int k = 0; k < 4; ++k) atomicAdd(tb + k, acc[k]);
}

__global__ void out_f(const float* __restrict__ A, const float* __restrict__ r,
                      const float* __restrict__ c, float* __restrict__ out) {
    long long g = ((long long)blockIdx.x * blockDim.x + threadIdx.x) * 4;
    int R = (int)(g >> 11);
    int b = R >> 11;
    int j = (int)(g & 2047);
    float rv = r[R];
    float4 a  = *reinterpret_cast<const float4*>(A + g);
    float4 cv = *reinterpret_cast<const float4*>(c + b * N + j);
    float4 o;
    o.x = rv * __expf(a.x) * cv.x;
    o.y = rv * __expf(a.y) * cv.y;
    o.z = rv * __expf(a.z) * cv.z;
    o.w = rv * __expf(a.w) * cv.w;
    *reinterpret_cast<float4*>(out + g) = o;
}

extern "C" void kernel_launch(void* const* d_in, const int* in_sizes, int n_in,
                              void* d_out, int out_size, void* d_ws, size_t ws_size,
                              hipStream_t stream) {
    const float* A = (const float*)d_in[0];
    float* out = (float*)d_out;
    const size_t E_bytes   = (size_t)NELEM * sizeof(__half);     // 128 MiB
    const size_t vec_bytes = (size_t)NR * sizeof(float);         // 128 KiB
    char* ws = (char*)d_ws;

    if (ws_size >= E_bytes + 3 * vec_bytes) {
        __half* E = (__half*)ws;
        float* r = (float*)(ws + E_bytes);
        float* c = r + NR;
        float* t = c + NR;
        init_vecs<<<NR / 256, 256, 0, stream>>>(r, c, t);
        exp_cast<<<(int)(NELEM / 8 / 256), 256, 0, stream>>>(A, E);
        for (int it = 0; it < 20; ++it) {
            row_pass_h<<<NR / 4, 256, 0, stream>>>(E, c, r);
            col_pass_h<<<NB * 64, 256, 0, stream>>>(E, r, t);
            c_update<<<NR / 256, 256, 0, stream>>>(c, t);
        }
        out_h<<<(int)(NELEM / 8 / 256), 256, 0, stream>>>(E, r, c, out);
    } else {
        float* r = (float*)ws;
        float* c = r + NR;
        float* t = c + NR;
        init_vecs<<<NR / 256, 256, 0, stream>>>(r, c, t);
        for (int it = 0; it < 20; ++it) {
            row_pass_f<<<NR / 4, 256, 0, stream>>>(A, c, r);
            col_pass_f<<<NB * 128, 256, 0, stream>>>(A, r, t);
            c_update<<<NR / 256, 256, 0, stream>>>(c, t);
        }
        out_f<<<(int)(NELEM / 4 / 256), 256, 0, stream>>>(A, r, c, out);
    }
}